// Round 7
// baseline (329.889 us; speedup 1.0000x reference)
//
#include <hip/hip_runtime.h>
#include <math.h>

// Tropical max/min-plus pseudo-matmul.
// out[b,u] = max_f(x[b,f] + w[f,u]) for u<128, min_f otherwise.
//
// R6 lesson: U=2 units/lane left LDS pipe as the pole (24.6k cyc/CU) and it
// doesn't overlap away. R7: U=4 (lane covers 4 units, wave covers ALL 256) ->
// LDS-pipe cost halves to 12.3k cyc/CU; w loads become dwordx4. The max/min
// boundary lands mid-wave -> branch-free per-lane sign fold: lanes>=32 compute
// s = fma(x,-1,-w) = -(x+w) (exact), uniform max accumulate, negate at store.
// __launch_bounds__(512,2): 2nd arg measured (R5) as CUDA-style blocks/CU ->
// 2 blk x 8 waves = 4 waves/SIMD -> 128 VGPR cap (budget ~100, no spill).
// Cost stack/CU: L2 w-stream 7.4us, VALU ~6.3us, LDS 5.1us.

#define FEAT  512
#define UNITS 256
#define BR    4     // rows per block
#define KW    64    // k per wave
#define NW    8     // waves per block

__device__ __forceinline__ float max3(float a, float b, float c) {
    return fmaxf(fmaxf(a, b), c);   // v_max3_f32
}

__device__ __forceinline__ float4 sgn4(float4 v, float s) {
    return make_float4(v.x * s, v.y * s, v.z * s, v.w * s);
}

// one quad = 4 consecutive k values
__device__ __forceinline__ void quad_compute(const float* __restrict__ xs,
                                             int xoff, const float4* __restrict__ wb,
                                             float sgn, float4* __restrict__ acc) {
    // fold sign into w once per quad (shared across all 4 rows)
    const float4 w0 = sgn4(wb[0], sgn);
    const float4 w1 = sgn4(wb[1], sgn);
    const float4 w2 = sgn4(wb[2], sgn);
    const float4 w3 = sgn4(wb[3], sgn);
    #pragma unroll
    for (int r = 0; r < BR; ++r) {
        // broadcast ds_read_b128: all 64 lanes same address, conflict-free
        const float4 a = *(const float4*)&xs[r * FEAT + xoff];
        float4 A = acc[r];
        A.x = max3(A.x, fmaf(a.x, sgn, w0.x), fmaf(a.y, sgn, w1.x));
        A.x = max3(A.x, fmaf(a.z, sgn, w2.x), fmaf(a.w, sgn, w3.x));
        A.y = max3(A.y, fmaf(a.x, sgn, w0.y), fmaf(a.y, sgn, w1.y));
        A.y = max3(A.y, fmaf(a.z, sgn, w2.y), fmaf(a.w, sgn, w3.y));
        A.z = max3(A.z, fmaf(a.x, sgn, w0.z), fmaf(a.y, sgn, w1.z));
        A.z = max3(A.z, fmaf(a.z, sgn, w2.z), fmaf(a.w, sgn, w3.z));
        A.w = max3(A.w, fmaf(a.x, sgn, w0.w), fmaf(a.y, sgn, w1.w));
        A.w = max3(A.w, fmaf(a.z, sgn, w2.w), fmaf(a.w, sgn, w3.w));
        acc[r] = A;
    }
}

__global__ __launch_bounds__(512, 2) void tropical_kernel(const float* __restrict__ x,
                                                          const float* __restrict__ w,
                                                          float* __restrict__ out) {
    __shared__ float lds[NW * BR * UNITS];   // 32 KB; x tile uses first 8 KB
    const int tid  = threadIdx.x;
    const int lane = tid & 63;
    const int wv   = __builtin_amdgcn_readfirstlane(tid >> 6);  // 0..7
    const int u0   = lane * 4;                                  // 0..252
    const float sgn = (lane < 32) ? 1.0f : -1.0f;               // min half negated
    const int row0 = blockIdx.x * BR;
    const int kb   = wv * KW;

    // ---- stage x tile (4 rows x 512 = 8 KB), one float4 per thread ----
    {
        const float4* src = (const float4*)(x + (size_t)row0 * FEAT);
        ((float4*)lds)[tid] = src[tid];
    }

    const float* wp = w + (size_t)kb * UNITS + u0;   // dwordx4, 1KB/wave-instr

    float4 acc[BR];
    #pragma unroll
    for (int r = 0; r < BR; ++r)
        acc[r] = make_float4(-__builtin_inff(), -__builtin_inff(),
                             -__builtin_inff(), -__builtin_inff());

    // software pipeline: A/B float4[4] buffers, quad (4-k) granularity
    float4 wA[4], wB[4];
    #pragma unroll
    for (int k = 0; k < 4; ++k) wA[k] = *(const float4*)(wp + (size_t)k * UNITS);

    __syncthreads();   // x tile visible

    #pragma unroll
    for (int q = 0; q < KW / 4; q += 2) {
        #pragma unroll
        for (int k = 0; k < 4; ++k)
            wB[k] = *(const float4*)(wp + (size_t)((q + 1) * 4 + k) * UNITS);
        quad_compute(lds, kb + q * 4, wA, sgn, acc);
        if (q + 2 < KW / 4) {
            #pragma unroll
            for (int k = 0; k < 4; ++k)
                wA[k] = *(const float4*)(wp + (size_t)((q + 2) * 4 + k) * UNITS);
        }
        quad_compute(lds, kb + (q + 1) * 4, wB, sgn, acc);
    }

    // ---- combine 8 k-partials via LDS (reuses x region; 32 KB) ----
    __syncthreads();   // all waves done reading x tile
    #pragma unroll
    for (int r = 0; r < BR; ++r)
        *(float4*)&lds[((wv * BR + r) * UNITS) + u0] = acc[r];
    __syncthreads();

    // thread -> output pair: r = tid>>7, units up0..up0+1
    const int r   = tid >> 7;
    const int up0 = (tid & 127) * 2;
    float2 v = *(const float2*)&lds[(0 * BR + r) * UNITS + up0];
    #pragma unroll
    for (int j = 1; j < NW; ++j) {
        const float2 p = *(const float2*)&lds[(j * BR + r) * UNITS + up0];
        v.x = fmaxf(v.x, p.x);
        v.y = fmaxf(v.y, p.y);
    }
    const float so = (up0 < 128) ? 1.0f : -1.0f;   // undo negation for min half
    *(float2*)&out[(size_t)(row0 + r) * UNITS + up0] = make_float2(v.x * so, v.y * so);
}

extern "C" void kernel_launch(void* const* d_in, const int* in_sizes, int n_in,
                              void* d_out, int out_size, void* d_ws, size_t ws_size,
                              hipStream_t stream) {
    const float* x = (const float*)d_in[0];   // (2048, 512)
    const float* w = (const float*)d_in[1];   // (512, 256)
    float* out = (float*)d_out;               // (2048, 256)

    // 512 row-groups x 8 waves = 4096 waves = 4/SIMD, 2 blocks/CU
    tropical_kernel<<<dim3(2048 / BR), dim3(512), 0, stream>>>(x, w, out);
}

// Round 8
// 68.412 us; speedup vs baseline: 4.8221x; 4.8221x over previous
//
#include <hip/hip_runtime.h>
#include <math.h>

// Tropical max/min-plus pseudo-matmul.
// out[b,u] = max_f(x[b,f] + w[f,u]) for u<128, min_f otherwise.
//
// R7 lesson: manual A/B double-buffer + full unroll => compiler hoists all
// w-loads, ~250+ VGPR live, massive scratch spill (916 MB traffic) even at the
// 128 cap. launch_bounds 2nd arg CONFIRMED CUDA-style blocks/CU on this
// toolchain (R5: (512,4)->64 VGPR; R7: (512,2)->128 VGPR).
// R8: same U=4 structure (lane = 4 units, wave = all 256 units, per-lane sign
// fold; LDS x-broadcast is the invariant 12.3k cyc/CU), but NO manual
// pipeline and #pragma unroll 1 on the k-loop -> ~70 VGPR live, no spill.
// Latency hidden by 4 waves/SIMD. Cost stack/CU: L2 w 7.4us, VALU 5.8, LDS 5.1.

#define FEAT  512
#define UNITS 256
#define BR    4     // rows per block
#define KW    64    // k per wave
#define NW    8     // waves per block

__device__ __forceinline__ float max3(float a, float b, float c) {
    return fmaxf(fmaxf(a, b), c);   // v_max3_f32
}

__global__ __launch_bounds__(512, 2) void tropical_kernel(const float* __restrict__ x,
                                                          const float* __restrict__ w,
                                                          float* __restrict__ out) {
    __shared__ float lds[NW * BR * UNITS];   // 32 KB; x tile uses first 8 KB
    const int tid  = threadIdx.x;
    const int lane = tid & 63;
    const int wv   = __builtin_amdgcn_readfirstlane(tid >> 6);  // 0..7
    const int u0   = lane * 4;                                  // 0..252
    const float sgn = (lane < 32) ? 1.0f : -1.0f;               // min half negated
    const int row0 = blockIdx.x * BR;
    const int kb   = wv * KW;

    // ---- stage x tile (4 rows x 512 = 8 KB), one float4 per thread ----
    {
        const float4* src = (const float4*)(x + (size_t)row0 * FEAT);
        ((float4*)lds)[tid] = src[tid];
    }

    const float* wp = w + (size_t)kb * UNITS + u0;   // dwordx4, 1KB/wave-instr

    float4 acc[BR];
    #pragma unroll
    for (int r = 0; r < BR; ++r)
        acc[r] = make_float4(-__builtin_inff(), -__builtin_inff(),
                             -__builtin_inff(), -__builtin_inff());

    __syncthreads();   // x tile visible

    // one iteration = one k-quad (4 k values x 4 units). No manual pipeline:
    // unroll 1 keeps exactly one w-quad (16 VGPR) in flight -> no spill.
    #pragma unroll 1
    for (int q = 0; q < KW / 4; ++q) {
        float4 wq[4];
        #pragma unroll
        for (int k = 0; k < 4; ++k)
            wq[k] = *(const float4*)(wp + (size_t)(q * 4 + k) * UNITS);

        // fold per-lane sign into w once per quad
        const float4 w0 = make_float4(wq[0].x*sgn, wq[0].y*sgn, wq[0].z*sgn, wq[0].w*sgn);
        const float4 w1 = make_float4(wq[1].x*sgn, wq[1].y*sgn, wq[1].z*sgn, wq[1].w*sgn);
        const float4 w2 = make_float4(wq[2].x*sgn, wq[2].y*sgn, wq[2].z*sgn, wq[2].w*sgn);
        const float4 w3 = make_float4(wq[3].x*sgn, wq[3].y*sgn, wq[3].z*sgn, wq[3].w*sgn);

        #pragma unroll
        for (int r = 0; r < BR; ++r) {
            // broadcast ds_read_b128: all 64 lanes same address, conflict-free
            const float4 a = *(const float4*)&lds[r * FEAT + kb + q * 4];
            float4 A = acc[r];
            A.x = max3(A.x, fmaf(a.x, sgn, w0.x), fmaf(a.y, sgn, w1.x));
            A.x = max3(A.x, fmaf(a.z, sgn, w2.x), fmaf(a.w, sgn, w3.x));
            A.y = max3(A.y, fmaf(a.x, sgn, w0.y), fmaf(a.y, sgn, w1.y));
            A.y = max3(A.y, fmaf(a.z, sgn, w2.y), fmaf(a.w, sgn, w3.y));
            A.z = max3(A.z, fmaf(a.x, sgn, w0.z), fmaf(a.y, sgn, w1.z));
            A.z = max3(A.z, fmaf(a.z, sgn, w2.z), fmaf(a.w, sgn, w3.z));
            A.w = max3(A.w, fmaf(a.x, sgn, w0.w), fmaf(a.y, sgn, w1.w));
            A.w = max3(A.w, fmaf(a.z, sgn, w2.w), fmaf(a.w, sgn, w3.w));
            acc[r] = A;
        }
    }

    // ---- combine 8 k-partials via LDS (reuses x region; 32 KB) ----
    __syncthreads();   // all waves done reading x tile
    #pragma unroll
    for (int r = 0; r < BR; ++r)
        *(float4*)&lds[((wv * BR + r) * UNITS) + u0] = acc[r];
    __syncthreads();

    // thread -> output pair: r = tid>>7, units up0..up0+1
    const int r   = tid >> 7;
    const int up0 = (tid & 127) * 2;
    float2 v = *(const float2*)&lds[(0 * BR + r) * UNITS + up0];
    #pragma unroll
    for (int j = 1; j < NW; ++j) {
        const float2 p = *(const float2*)&lds[(j * BR + r) * UNITS + up0];
        v.x = fmaxf(v.x, p.x);
        v.y = fmaxf(v.y, p.y);
    }
    const float so = (up0 < 128) ? 1.0f : -1.0f;   // undo negation for min half
    *(float2*)&out[(size_t)(row0 + r) * UNITS + up0] = make_float2(v.x * so, v.y * so);
}

extern "C" void kernel_launch(void* const* d_in, const int* in_sizes, int n_in,
                              void* d_out, int out_size, void* d_ws, size_t ws_size,
                              hipStream_t stream) {
    const float* x = (const float*)d_in[0];   // (2048, 512)
    const float* w = (const float*)d_in[1];   // (512, 256)
    float* out = (float*)d_out;               // (2048, 256)

    // 512 row-groups x 8 waves = 4096 waves = 4/SIMD, 2 blocks/CU
    tropical_kernel<<<dim3(2048 / BR), dim3(512), 0, stream>>>(x, w, out);
}

// Round 9
// 67.816 us; speedup vs baseline: 4.8645x; 1.0088x over previous
//
#include <hip/hip_runtime.h>
#include <math.h>

// Tropical max/min-plus pseudo-matmul.
// out[b,u] = max_f(x[b,f] + w[f,u]) for u<128, min_f otherwise.
//
// R8 lesson: clean (no-spill) kernels plateau ~24us while per-pipe models say
// 5-8us; the pole that didn't move between R6/R8 is the per-wave w re-read
// (L2 stream = 1 GB / BR). R9 pulls the BR lever: BR=8, 1024-thr blocks
// (16 waves k-split, KW=32), 256 blocks = 1/CU, still 4 waves/SIMD.
// w-stream 256->128 MB. acc 32 + w 16 + addr ~30 => ~100 VGPR, cap 128 via
// launch_bounds(1024,1) (CUDA-style blocks/CU semantics measured R5/R7).
// unroll 1 on k-loop (R7: manual pipelines+unroll => hoist => spill).
// Poles/CU: LDS 5.1us (invariant), VALU ~4.4us, L2-w ~3.7us.

#define FEAT  512
#define UNITS 256
#define BR    8     // rows per block
#define KW    32    // k per wave
#define NW    16    // waves per block

__device__ __forceinline__ float max3(float a, float b, float c) {
    return fmaxf(fmaxf(a, b), c);   // v_max3_f32
}

__global__ __launch_bounds__(1024, 1) void tropical_kernel(const float* __restrict__ x,
                                                           const float* __restrict__ w,
                                                           float* __restrict__ out) {
    __shared__ float lds[NW * BR * UNITS];   // 128 KB; x tile uses first 16 KB
    const int tid  = threadIdx.x;
    const int lane = tid & 63;
    const int wv   = __builtin_amdgcn_readfirstlane(tid >> 6);  // 0..15
    const int u0   = lane * 4;                                  // 0..252
    const float sgn = (lane < 32) ? 1.0f : -1.0f;               // min half negated
    const int row0 = blockIdx.x * BR;
    const int kb   = wv * KW;

    // ---- stage x tile (8 rows x 512 = 16 KB), one float4 per thread ----
    {
        const float4* src = (const float4*)(x + (size_t)row0 * FEAT);
        ((float4*)lds)[tid] = src[tid];
    }

    const float* wp = w + (size_t)kb * UNITS + u0;   // dwordx4, 1KB/wave-instr

    float4 acc[BR];
    #pragma unroll
    for (int r = 0; r < BR; ++r)
        acc[r] = make_float4(-__builtin_inff(), -__builtin_inff(),
                             -__builtin_inff(), -__builtin_inff());

    __syncthreads();   // x tile visible

    // one iteration = one k-quad (4 k x 4 units x 8 rows = 128 MACs/lane).
    // unroll 1: exactly one w-quad (16 VGPR) in flight -> no hoist, no spill.
    #pragma unroll 1
    for (int q = 0; q < KW / 4; ++q) {
        float4 wq[4];
        #pragma unroll
        for (int k = 0; k < 4; ++k)
            wq[k] = *(const float4*)(wp + (size_t)(q * 4 + k) * UNITS);

        // fold per-lane sign into w once per quad (shared across 8 rows)
        const float4 w0 = make_float4(wq[0].x*sgn, wq[0].y*sgn, wq[0].z*sgn, wq[0].w*sgn);
        const float4 w1 = make_float4(wq[1].x*sgn, wq[1].y*sgn, wq[1].z*sgn, wq[1].w*sgn);
        const float4 w2 = make_float4(wq[2].x*sgn, wq[2].y*sgn, wq[2].z*sgn, wq[2].w*sgn);
        const float4 w3 = make_float4(wq[3].x*sgn, wq[3].y*sgn, wq[3].z*sgn, wq[3].w*sgn);

        #pragma unroll
        for (int r = 0; r < BR; ++r) {
            // broadcast ds_read_b128: all 64 lanes same address, conflict-free
            const float4 a = *(const float4*)&lds[r * FEAT + kb + q * 4];
            float4 A = acc[r];
            A.x = max3(A.x, fmaf(a.x, sgn, w0.x), fmaf(a.y, sgn, w1.x));
            A.x = max3(A.x, fmaf(a.z, sgn, w2.x), fmaf(a.w, sgn, w3.x));
            A.y = max3(A.y, fmaf(a.x, sgn, w0.y), fmaf(a.y, sgn, w1.y));
            A.y = max3(A.y, fmaf(a.z, sgn, w2.y), fmaf(a.w, sgn, w3.y));
            A.z = max3(A.z, fmaf(a.x, sgn, w0.z), fmaf(a.y, sgn, w1.z));
            A.z = max3(A.z, fmaf(a.z, sgn, w2.z), fmaf(a.w, sgn, w3.z));
            A.w = max3(A.w, fmaf(a.x, sgn, w0.w), fmaf(a.y, sgn, w1.w));
            A.w = max3(A.w, fmaf(a.z, sgn, w2.w), fmaf(a.w, sgn, w3.w));
            acc[r] = A;
        }
    }

    // ---- combine 16 k-partials via LDS (reuses x region; 128 KB) ----
    __syncthreads();   // all waves done reading x tile
    #pragma unroll
    for (int r = 0; r < BR; ++r)
        *(float4*)&lds[((wv * BR + r) * UNITS) + u0] = acc[r];
    __syncthreads();

    // thread -> output pair: r = tid>>7 (0..7), units up0..up0+1
    const int r   = tid >> 7;
    const int up0 = (tid & 127) * 2;
    float2 v = *(const float2*)&lds[(0 * BR + r) * UNITS + up0];
    #pragma unroll
    for (int j = 1; j < NW; ++j) {
        const float2 p = *(const float2*)&lds[(j * BR + r) * UNITS + up0];
        v.x = fmaxf(v.x, p.x);
        v.y = fmaxf(v.y, p.y);
    }
    const float so = (up0 < 128) ? 1.0f : -1.0f;   // undo negation for min half
    *(float2*)&out[(size_t)(row0 + r) * UNITS + up0] = make_float2(v.x * so, v.y * so);
}

extern "C" void kernel_launch(void* const* d_in, const int* in_sizes, int n_in,
                              void* d_out, int out_size, void* d_ws, size_t ws_size,
                              hipStream_t stream) {
    const float* x = (const float*)d_in[0];   // (2048, 512)
    const float* w = (const float*)d_in[1];   // (512, 256)
    float* out = (float*)d_out;               // (2048, 256)

    // 256 blocks x 16 waves = 4096 waves = 4/SIMD, exactly 1 block per CU
    tropical_kernel<<<dim3(2048 / BR), dim3(1024), 0, stream>>>(x, w, out);
}